// Round 5
// baseline (701.636 us; speedup 1.0000x reference)
//
#include <hip/hip_runtime.h>
#include <hip/hip_bf16.h>

#define EPS 1e-5f
#define NBLK 768

typedef __attribute__((ext_vector_type(8))) short short8;
typedef __attribute__((ext_vector_type(4))) float floatx4;

__device__ inline float b2f(short s) {
    union { unsigned u; float f; } v;
    v.u = ((unsigned)(unsigned short)s) << 16;
    return v.f;
}
__device__ inline float sigmoidf_(float x) { return 1.f / (1.f + __expf(-x)); }
__device__ inline float tanhf_(float x) { return 1.f - 2.f / (__expf(2.f * x) + 1.f); }

__device__ inline void load_lds16(const void* g, void* l) {
    __builtin_amdgcn_global_load_lds(
        (const __attribute__((address_space(1))) void*)g,
        (__attribute__((address_space(3))) void*)l, 16, 0, 0);
}

// Single-use monotonic grid barrier: counter pre-zeroed by host memset.
// All NBLK blocks are co-resident (launch_bounds(256,3) + LDS 34KiB => >=3
// blocks/CU * 256 CU = 768 slots), so the spin always terminates.
__device__ __forceinline__ void gridbar(unsigned* c) {
    __threadfence();
    __syncthreads();
    if (threadIdx.x == 0) {
        atomicAdd(c, 1u);
        while (atomicAdd(c, 0u) < NBLK) __builtin_amdgcn_s_sleep(2);
    }
    __syncthreads();
    __threadfence();
}

// ---------------------------------------------------------------------------
// gemm tile body (verbatim from the verified R4 gemm_dual): 128x128 tile,
// BK=64, 4 waves (2x2), 4x4 mfma_f32_16x16x32_bf16, global_load_lds staging
// with XOR-swizzled chunks, epilogue via padded LDS (stride 136).
// ---------------------------------------------------------------------------
__device__ __forceinline__ void gemm_tile(
    const __hip_bfloat16* __restrict__ A, const __hip_bfloat16* __restrict__ W,
    const float* __restrict__ bias, __hip_bfloat16* __restrict__ out,
    int K, int m0, int n0, __hip_bfloat16* smem)
{
    __hip_bfloat16* sA = smem;
    __hip_bfloat16* sB = smem + 8192;
    const int t    = threadIdx.x;
    const int lane = t & 63;
    const int wave = t >> 6;
    const int quad = lane >> 4;
    const int rl   = lane & 15;
    const int wm   = (wave >> 1) * 64;
    const int wn   = (wave & 1) * 64;

    floatx4 acc[4][4];
    #pragma unroll
    for (int i = 0; i < 4; ++i)
        #pragma unroll
        for (int j = 0; j < 4; ++j)
            acc[i][j] = (floatx4){0.f, 0.f, 0.f, 0.f};

    int srow[4], scol[4];
    #pragma unroll
    for (int i = 0; i < 4; ++i) {
        const int cl  = (wave * 4 + i) * 64 + lane;
        const int row = cl >> 3;
        srow[i] = row;
        scol[i] = ((cl & 7) ^ (row & 7)) * 8;
    }

    for (int k0 = 0; k0 < K; k0 += 64) {
        __syncthreads();
        #pragma unroll
        for (int i = 0; i < 4; ++i) {
            load_lds16(A + (size_t)(m0 + srow[i]) * K + k0 + scol[i], sA + (wave * 4 + i) * 512);
            load_lds16(W + (size_t)(n0 + srow[i]) * K + k0 + scol[i], sB + (wave * 4 + i) * 512);
        }
        __syncthreads();
        #pragma unroll
        for (int kk = 0; kk < 2; ++kk) {
            short8 aF[4], bF[4];
            #pragma unroll
            for (int i = 0; i < 4; ++i) {
                const int r = wm + i * 16 + rl;
                const int c = kk * 4 + quad;
                aF[i] = *(const short8*)(sA + (r * 8 + (c ^ (r & 7))) * 8);
            }
            #pragma unroll
            for (int j = 0; j < 4; ++j) {
                const int r = wn + j * 16 + rl;
                const int c = kk * 4 + quad;
                bF[j] = *(const short8*)(sB + (r * 8 + (c ^ (r & 7))) * 8);
            }
            #pragma unroll
            for (int i = 0; i < 4; ++i)
                #pragma unroll
                for (int j = 0; j < 4; ++j)
                    acc[i][j] = __builtin_amdgcn_mfma_f32_16x16x32_bf16(aF[i], bF[j], acc[i][j], 0, 0, 0);
        }
    }

    __syncthreads();
    #pragma unroll
    for (int j = 0; j < 4; ++j) {
        const int col = wn + j * 16 + rl;
        const float bv = bias[n0 + col];
        #pragma unroll
        for (int i = 0; i < 4; ++i) {
            const int rbase = wm + i * 16 + quad * 4;
            #pragma unroll
            for (int r = 0; r < 4; ++r)
                smem[(rbase + r) * 136 + col] = __float2bfloat16(acc[i][j][r] + bv);
        }
    }
    __syncthreads();
    #pragma unroll
    for (int p = 0; p < 8; ++p) {
        const int ch  = p * 256 + t;
        const int row = ch >> 4;
        const int c8  = (ch & 15) * 8;
        short8 v = *(const short8*)(smem + row * 136 + c8);
        *(short8*)(out + (size_t)(m0 + row) * 4096 + n0 + c8) = v;
    }
}

// ---------------------------------------------------------------------------
// LN+gates for rows {2*vb, 2*vb+1} (verified R0 structure, 256 thr, 2 rows).
// Pi/Ph fragments held as bf16 short8 (not f32) to stay under the 168-VGPR
// cap imposed by launch_bounds(256,3); converted on use (values identical).
// ---------------------------------------------------------------------------
__device__ __forceinline__ void ln2rows(
    int vb, const __hip_bfloat16* __restrict__ Pi, const __hip_bfloat16* __restrict__ Ph,
    const float* __restrict__ c_prev,
    const float* __restrict__ g_in, const float* __restrict__ b_in,
    const float* __restrict__ g_hid, const float* __restrict__ b_hid,
    const float* __restrict__ g_cell, const float* __restrict__ b_cell,
    float* __restrict__ h_out, float* __restrict__ c_out, float* sredf)
{
    const int t    = threadIdx.x;
    const int half = t >> 7;
    const int tt   = t & 127;
    const int wave = t >> 6;
    const int row  = vb * 2 + half;

    const __hip_bfloat16* pi = Pi + (size_t)row * 4096;
    const __hip_bfloat16* ph = Ph + (size_t)row * 4096;
    const int j0 = tt * 8;

    short8 vi[4], vh[4];
    float si = 0.f, sqi = 0.f, sh = 0.f, sqh = 0.f;
    #pragma unroll
    for (int g = 0; g < 4; ++g) {
        vi[g] = *(const short8*)(pi + g * 1024 + j0);
        vh[g] = *(const short8*)(ph + g * 1024 + j0);
        #pragma unroll
        for (int e = 0; e < 8; ++e) {
            const float a = b2f(vi[g][e]); si += a; sqi += a * a;
            const float b = b2f(vh[g][e]); sh += b; sqh += b * b;
        }
    }
    floatx4 cp0 = *(const floatx4*)(c_prev + (size_t)row * 1024 + j0);
    floatx4 cp1 = *(const floatx4*)(c_prev + (size_t)row * 1024 + j0 + 4);

    #pragma unroll
    for (int mask = 1; mask <= 32; mask <<= 1) {
        si += __shfl_xor(si, mask); sqi += __shfl_xor(sqi, mask);
        sh += __shfl_xor(sh, mask); sqh += __shfl_xor(sqh, mask);
    }
    if ((t & 63) == 0) {
        sredf[wave * 6 + 0] = si; sredf[wave * 6 + 1] = sqi;
        sredf[wave * 6 + 2] = sh; sredf[wave * 6 + 3] = sqh;
    }
    __syncthreads();
    const int wb = half * 2;
    si  = sredf[wb * 6 + 0] + sredf[wb * 6 + 6];
    sqi = sredf[wb * 6 + 1] + sredf[wb * 6 + 7];
    sh  = sredf[wb * 6 + 2] + sredf[wb * 6 + 8];
    sqh = sredf[wb * 6 + 3] + sredf[wb * 6 + 9];

    const float mu_i = si * (1.f / 4096.f);
    const float rs_i = rsqrtf(sqi * (1.f / 4096.f) - mu_i * mu_i + EPS);
    const float mu_h = sh * (1.f / 4096.f);
    const float rs_h = rsqrtf(sqh * (1.f / 4096.f) - mu_h * mu_h + EPS);

    float comb[4][8];
    #pragma unroll
    for (int g = 0; g < 4; ++g) {
        const int col = g * 1024 + j0;
        floatx4 gi0  = *(const floatx4*)(g_in  + col);
        floatx4 gi1  = *(const floatx4*)(g_in  + col + 4);
        floatx4 bi0  = *(const floatx4*)(b_in  + col);
        floatx4 bi1  = *(const floatx4*)(b_in  + col + 4);
        floatx4 gh0  = *(const floatx4*)(g_hid + col);
        floatx4 gh1  = *(const floatx4*)(g_hid + col + 4);
        floatx4 bh0  = *(const floatx4*)(b_hid + col);
        floatx4 bh1  = *(const floatx4*)(b_hid + col + 4);
        #pragma unroll
        for (int e = 0; e < 4; ++e) {
            comb[g][e]     = (b2f(vi[g][e])     - mu_i) * rs_i * gi0[e] + bi0[e]
                           + (b2f(vh[g][e])     - mu_h) * rs_h * gh0[e] + bh0[e];
            comb[g][e + 4] = (b2f(vi[g][e + 4]) - mu_i) * rs_i * gi1[e] + bi1[e]
                           + (b2f(vh[g][e + 4]) - mu_h) * rs_h * gh1[e] + bh1[e];
        }
    }

    float cn[8], ov[8];
    float sc = 0.f, scq = 0.f;
    #pragma unroll
    for (int e = 0; e < 8; ++e) {
        const float iv = sigmoidf_(comb[0][e]);
        const float fv = sigmoidf_(comb[1][e]);
        const float gv = tanhf_(comb[2][e]);
        ov[e] = sigmoidf_(comb[3][e]);
        const float cpv = (e < 4) ? cp0[e] : cp1[e - 4];
        const float c = fv * cpv + iv * gv;
        cn[e] = c; sc += c; scq += c * c;
    }
    #pragma unroll
    for (int mask = 1; mask <= 32; mask <<= 1) {
        sc += __shfl_xor(sc, mask); scq += __shfl_xor(scq, mask);
    }
    if ((t & 63) == 0) { sredf[wave * 6 + 4] = sc; sredf[wave * 6 + 5] = scq; }
    __syncthreads();
    sc  = sredf[wb * 6 + 4] + sredf[wb * 6 + 10];
    scq = sredf[wb * 6 + 5] + sredf[wb * 6 + 11];
    const float mu_c = sc * (1.f / 1024.f);
    const float rs_c = rsqrtf(scq * (1.f / 1024.f) - mu_c * mu_c + EPS);

    floatx4 gc0 = *(const floatx4*)(g_cell + j0);
    floatx4 gc1 = *(const floatx4*)(g_cell + j0 + 4);
    floatx4 bc0 = *(const floatx4*)(b_cell + j0);
    floatx4 bc1 = *(const floatx4*)(b_cell + j0 + 4);
    floatx4 hv0, hv1, cv0, cv1;
    #pragma unroll
    for (int e = 0; e < 4; ++e) {
        const float nc0 = (cn[e]     - mu_c) * rs_c * gc0[e] + bc0[e];
        const float nc1 = (cn[e + 4] - mu_c) * rs_c * gc1[e] + bc1[e];
        hv0[e] = ov[e] * tanhf_(nc0);
        hv1[e] = ov[e + 4] * tanhf_(nc1);
        cv0[e] = cn[e];
        cv1[e] = cn[e + 4];
    }
    float* hp = h_out + (size_t)row * 1024 + j0;
    float* cpout = c_out + (size_t)row * 1024 + j0;
    *(floatx4*)(hp) = hv0;     *(floatx4*)(hp + 4) = hv1;
    *(floatx4*)(cpout) = cv0;  *(floatx4*)(cpout + 4) = cv1;
}

// ---------------------------------------------------------------------------
// Fused persistent kernel: cvt -> gridbar -> dual gemm -> gridbar -> ln+gates.
// 768 blocks co-resident; perfect gemm balance (512 blocks x 4 K=1024 tiles,
// 256 blocks x 8 K=512 tiles = 64 K-iterations each).
// ---------------------------------------------------------------------------
__global__ __launch_bounds__(256, 3)
void fused_cell(const float* __restrict__ x, const float* __restrict__ h_prev,
                const float* __restrict__ c_prev,
                const float* __restrict__ Wi, const float* __restrict__ bi,
                const float* __restrict__ Wh, const float* __restrict__ bh,
                const float* __restrict__ g_in, const float* __restrict__ b_in,
                const float* __restrict__ g_hid, const float* __restrict__ b_hid,
                const float* __restrict__ g_cell, const float* __restrict__ b_cell,
                __hip_bfloat16* __restrict__ xb, __hip_bfloat16* __restrict__ hb,
                __hip_bfloat16* __restrict__ Wib, __hip_bfloat16* __restrict__ Whb,
                __hip_bfloat16* __restrict__ Pi, __hip_bfloat16* __restrict__ Ph,
                float* __restrict__ h_out, float* __restrict__ c_out,
                unsigned* __restrict__ bar)
{
    __shared__ alignas(16) __hip_bfloat16 smem[17408];
    const int bid = blockIdx.x;

    // ---- phase A: fp32 -> bf16 (9216 virtual blocks, 12 each) ----
    for (int it = 0; it < 12; ++it) {
        const int v = bid + NBLK * it;
        const float* s; __hip_bfloat16* d; int off;
        if (v < 2048)      { s = x;      d = xb;  off = v; }
        else if (v < 6144) { s = h_prev; d = hb;  off = v - 2048; }
        else if (v < 7168) { s = Wi;     d = Wib; off = v - 6144; }
        else               { s = Wh;     d = Whb; off = v - 7168; }
        const int idx = (off * 256 + threadIdx.x) * 8;
        float4 v0 = *(const float4*)(s + idx);
        float4 v1 = *(const float4*)(s + idx + 4);
        union { short8 sv; __hip_bfloat16 h[8]; } u;
        u.h[0] = __float2bfloat16(v0.x); u.h[1] = __float2bfloat16(v0.y);
        u.h[2] = __float2bfloat16(v0.z); u.h[3] = __float2bfloat16(v0.w);
        u.h[4] = __float2bfloat16(v1.x); u.h[5] = __float2bfloat16(v1.y);
        u.h[6] = __float2bfloat16(v1.z); u.h[7] = __float2bfloat16(v1.w);
        *(short8*)(d + idx) = u.sv;
    }
    gridbar(bar);

    // ---- phase B: dual GEMM, perfectly balanced ----
    if (bid < 512) {
        #pragma unroll 1
        for (int j = 0; j < 4; ++j) {
            const int tile = bid * 4 + j;          // 0..2047, K=1024
            gemm_tile(hb, Whb, bh, Ph, 1024, (tile >> 5) * 128, (tile & 31) * 128, smem);
        }
    } else {
        #pragma unroll 1
        for (int j = 0; j < 8; ++j) {
            const int tile = (bid - 512) * 8 + j;  // 0..2047, K=512
            gemm_tile(xb, Wib, bi, Pi, 512, (tile >> 5) * 128, (tile & 31) * 128, smem);
        }
    }
    gridbar(bar + 1);

    // ---- phase C: LN + gates (4096 virtual 2-row blocks) ----
    for (int k = 0; k < 6; ++k) {
        const int v = bid + NBLK * k;
        if (v < 4096)
            ln2rows(v, Pi, Ph, c_prev, g_in, b_in, g_hid, b_hid, g_cell, b_cell,
                    h_out, c_out, (float*)smem);
    }
}

// ---------------------------------------------------------------------------
// Fallback standalone kernels (exact R4 path, used only if ws lacks room for
// the barrier counters).
// ---------------------------------------------------------------------------
__global__ __launch_bounds__(256)
void cvt_bf16(const float* __restrict__ s0, __hip_bfloat16* __restrict__ d0,
              const float* __restrict__ s1, __hip_bfloat16* __restrict__ d1,
              const float* __restrict__ s2, __hip_bfloat16* __restrict__ d2,
              const float* __restrict__ s3, __hip_bfloat16* __restrict__ d3) {
    const int b = blockIdx.x;
    const float* s; __hip_bfloat16* d; int off;
    if (b < 2048)      { s = s0; d = d0; off = b; }
    else if (b < 6144) { s = s1; d = d1; off = b - 2048; }
    else if (b < 7168) { s = s2; d = d2; off = b - 6144; }
    else               { s = s3; d = d3; off = b - 7168; }
    const int idx = (off * 256 + threadIdx.x) * 8;
    float4 v0 = *(const float4*)(s + idx);
    float4 v1 = *(const float4*)(s + idx + 4);
    union { short8 sv; __hip_bfloat16 h[8]; } u;
    u.h[0] = __float2bfloat16(v0.x); u.h[1] = __float2bfloat16(v0.y);
    u.h[2] = __float2bfloat16(v0.z); u.h[3] = __float2bfloat16(v0.w);
    u.h[4] = __float2bfloat16(v1.x); u.h[5] = __float2bfloat16(v1.y);
    u.h[6] = __float2bfloat16(v1.z); u.h[7] = __float2bfloat16(v1.w);
    *(short8*)(d + idx) = u.sv;
}

__global__ __launch_bounds__(256, 3)
void gemm_dual(const __hip_bfloat16* __restrict__ A0, const __hip_bfloat16* __restrict__ W0,
               const float* __restrict__ bias0, __hip_bfloat16* __restrict__ out0, int K0,
               const __hip_bfloat16* __restrict__ A1, const __hip_bfloat16* __restrict__ W1,
               const float* __restrict__ bias1, __hip_bfloat16* __restrict__ out1, int K1) {
    __shared__ alignas(16) __hip_bfloat16 smem[17408];
    const __hip_bfloat16* A;  const __hip_bfloat16* W;
    const float* bias;        __hip_bfloat16* out;  int K;
    if (blockIdx.z == 0) { A = A0; W = W0; bias = bias0; out = out0; K = K0; }
    else                 { A = A1; W = W1; bias = bias1; out = out1; K = K1; }
    gemm_tile(A, W, bias, out, K, blockIdx.y * 128, blockIdx.x * 128, smem);
}

__global__ __launch_bounds__(256)
void ln_gates(const __hip_bfloat16* __restrict__ Pi, const __hip_bfloat16* __restrict__ Ph,
              const float* __restrict__ c_prev,
              const float* __restrict__ g_in, const float* __restrict__ b_in,
              const float* __restrict__ g_hid, const float* __restrict__ b_hid,
              const float* __restrict__ g_cell, const float* __restrict__ b_cell,
              float* __restrict__ h_out, float* __restrict__ c_out) {
    __shared__ float sredf[24];
    ln2rows(blockIdx.x, Pi, Ph, c_prev, g_in, b_in, g_hid, b_hid, g_cell, b_cell,
            h_out, c_out, sredf);
}

// ---------------------------------------------------------------------------
extern "C" void kernel_launch(void* const* d_in, const int* in_sizes, int n_in,
                              void* d_out, int out_size, void* d_ws, size_t ws_size,
                              hipStream_t stream) {
    const float* x      = (const float*)d_in[0];
    const float* h_prev = (const float*)d_in[1];
    const float* c_prev = (const float*)d_in[2];
    const float* Wi     = (const float*)d_in[3];
    const float* bi     = (const float*)d_in[4];
    const float* Wh     = (const float*)d_in[5];
    const float* bh     = (const float*)d_in[6];
    const float* g_in   = (const float*)d_in[7];
    const float* b_in   = (const float*)d_in[8];
    const float* g_hid  = (const float*)d_in[9];
    const float* b_hid  = (const float*)d_in[10];
    const float* g_cell = (const float*)d_in[11];
    const float* b_cell = (const float*)d_in[12];

    __hip_bfloat16* Pi = (__hip_bfloat16*)d_ws;               // 64 MiB
    __hip_bfloat16* Ph = Pi + (size_t)8192 * 4096;            // 64 MiB

    const int NX = 8192 * 512, NH = 8192 * 1024;
    __hip_bfloat16* xb  = (__hip_bfloat16*)d_out;             // scratch in d_out
    __hip_bfloat16* hb  = xb + NX;
    __hip_bfloat16* Wib = hb + NH;
    __hip_bfloat16* Whb = Wib + 4096 * 512;

    float* h_out = (float*)d_out;
    float* c_out = h_out + (size_t)8192 * 1024;

    const size_t barOff = (size_t)134217728;                  // after Pi+Ph
    if (ws_size >= barOff + 16) {
        unsigned* bar = (unsigned*)((char*)d_ws + barOff);
        hipMemsetAsync(bar, 0, 16, stream);
        hipLaunchKernelGGL(fused_cell, dim3(NBLK), dim3(256), 0, stream,
                           x, h_prev, c_prev, Wi, bi, Wh, bh,
                           g_in, b_in, g_hid, b_hid, g_cell, b_cell,
                           xb, hb, Wib, Whb, Pi, Ph, h_out, c_out, bar);
    } else {
        hipLaunchKernelGGL(cvt_bf16, dim3(9216), dim3(256), 0, stream,
                           x, xb, h_prev, hb, Wi, Wib, Wh, Whb);
        hipLaunchKernelGGL(gemm_dual, dim3(32, 64, 2), dim3(256), 0, stream,
                           xb, Wib, bi, Pi, 512,
                           hb, Whb, bh, Ph, 1024);
        hipLaunchKernelGGL(ln_gates, dim3(4096), dim3(256), 0, stream, Pi, Ph, c_prev,
                           g_in, b_in, g_hid, b_hid, g_cell, b_cell, h_out, c_out);
    }
}

// Round 6
// 322.774 us; speedup vs baseline: 2.1738x; 2.1738x over previous
//
#include <hip/hip_runtime.h>
#include <hip/hip_bf16.h>

#define EPS 1e-5f

typedef __attribute__((ext_vector_type(8))) short short8;
typedef __attribute__((ext_vector_type(4))) float floatx4;

__device__ inline float b2f(short s) {
    union { unsigned u; float f; } v;
    v.u = ((unsigned)(unsigned short)s) << 16;
    return v.f;
}
__device__ inline float sigmoidf_(float x) { return 1.f / (1.f + __expf(-x)); }
__device__ inline float tanhf_(float x) { return 1.f - 2.f / (__expf(2.f * x) + 1.f); }

__device__ inline void load_lds16(const void* g, void* l) {
    __builtin_amdgcn_global_load_lds(
        (const __attribute__((address_space(1))) void*)g,
        (__attribute__((address_space(3))) void*)l, 16, 0, 0);
}

// ---------------------------------------------------------------------------
// fp32 -> bf16 converts (R4-verbatim). Exact 1-D grid (9216 blocks).
// ---------------------------------------------------------------------------
__global__ __launch_bounds__(256)
void cvt_bf16(const float* __restrict__ s0, __hip_bfloat16* __restrict__ d0,
              const float* __restrict__ s1, __hip_bfloat16* __restrict__ d1,
              const float* __restrict__ s2, __hip_bfloat16* __restrict__ d2,
              const float* __restrict__ s3, __hip_bfloat16* __restrict__ d3) {
    const int b = blockIdx.x;
    const float* s; __hip_bfloat16* d; int off;
    if (b < 2048)      { s = s0; d = d0; off = b; }
    else if (b < 6144) { s = s1; d = d1; off = b - 2048; }
    else if (b < 7168) { s = s2; d = d2; off = b - 6144; }
    else               { s = s3; d = d3; off = b - 7168; }
    const int idx = (off * 256 + threadIdx.x) * 8;
    float4 v0 = *(const float4*)(s + idx);
    float4 v1 = *(const float4*)(s + idx + 4);
    union { short8 sv; __hip_bfloat16 h[8]; } u;
    u.h[0] = __float2bfloat16(v0.x); u.h[1] = __float2bfloat16(v0.y);
    u.h[2] = __float2bfloat16(v0.z); u.h[3] = __float2bfloat16(v0.w);
    u.h[4] = __float2bfloat16(v1.x); u.h[5] = __float2bfloat16(v1.y);
    u.h[6] = __float2bfloat16(v1.z); u.h[7] = __float2bfloat16(v1.w);
    *(short8*)(d + idx) = u.sv;
}

// ---------------------------------------------------------------------------
// Dual GEMM, 256x256 tile, BK=64, 512 thr (8 waves), QUADRANT-PACKED phases:
// per phase ALL waves compute one 128x128 quadrant (wave = 64x32 of it), so
// phase (qm,qn) reads exactly half-tiles {A_qm, B_qn}.  Stage 1 half-tile of
// tile T+1 per phase, order [A0,B0,B1,A1]; quadrant order (0,0),(0,1),(1,1),
// (1,0).  Per-wave vmcnt ledger (2 loads/stage, verified for steady state,
// prologue, and last tile):
//   ph0 confirm T:{A0,B0} -> allow T:{B1,A1}+T1:{A0} = vmcnt(6)
//   ph1 confirm +T:{B1}   -> allow T:{A1}+T1:{A0,B0} = vmcnt(6)
//   ph2 confirm +T:{A1}   -> allow T1:{A0,B0,B1}     = vmcnt(6)
//   ph3 no wait (uses only regs: aF from ph2, bF0 from ph0)
//   last tile (nothing new issued): 4 / 2 / 0 / none.
// Barrier after each wait makes own-load confirmation global; tile-end
// barrier keeps T+1 ph0's stage (which writes buf[T&1]) after all T reads.
// Frag-reg reuse: aF reread per qm; bF0/bF1 persist -> 24 ds_read/tile/wave.
// R1 raced (waves spanned tile => every phase read everything); R3's drain0
// hit the documented 644-TF regime.  This is the counted-vmcnt fix.
// ---------------------------------------------------------------------------
#define STAGE_HALF(P, BASE, H, KZ, DSTB) do {                                   \
    const int rs0_ = (H) * 128 + r0;                                            \
    load_lds16((P) + (size_t)((BASE) + rs0_) * K + (KZ) + ((c0 ^ (rs0_ & 7)) << 3), \
               smem + (DSTB) + ((((H) << 10) + (wave << 6)) << 3));             \
    const int rs1_ = (H) * 128 + 64 + r0;                                       \
    load_lds16((P) + (size_t)((BASE) + rs1_) * K + (KZ) + ((c0 ^ (rs1_ & 7)) << 3), \
               smem + (DSTB) + ((((H) << 10) + 512 + (wave << 6)) << 3));       \
} while (0)

#define RDA(QM) do {                                                            \
    _Pragma("unroll")                                                           \
    for (int kk = 0; kk < 2; ++kk) {                                            \
        const int cc = kk * 4 + quad;                                           \
        _Pragma("unroll")                                                       \
        for (int i = 0; i < 4; ++i) {                                           \
            const int lr = wr * 64 + i * 16 + rl;                               \
            aF[kk][i] = *(const short8*)(Sb + (QM) * 8192 + lr * 64 + ((cc ^ rl7) << 3)); \
        }                                                                       \
    }                                                                           \
} while (0)

#define RDB(DST, QN) do {                                                       \
    _Pragma("unroll")                                                           \
    for (int kk = 0; kk < 2; ++kk) {                                            \
        const int cc = kk * 4 + quad;                                           \
        _Pragma("unroll")                                                       \
        for (int j = 0; j < 2; ++j) {                                           \
            const int lrb = wc * 32 + j * 16 + rl;                              \
            DST[kk][j] = *(const short8*)(Sb + 16384 + (QN) * 8192 + lrb * 64 + ((cc ^ rl7) << 3)); \
        }                                                                       \
    }                                                                           \
} while (0)

#define MFMAQ(QM, QN, BF) do {                                                  \
    __builtin_amdgcn_s_setprio(1);                                              \
    _Pragma("unroll")                                                           \
    for (int kk = 0; kk < 2; ++kk)                                              \
        _Pragma("unroll")                                                       \
        for (int i = 0; i < 4; ++i)                                             \
            _Pragma("unroll")                                                   \
            for (int j = 0; j < 2; ++j)                                         \
                acc[QM][QN][i][j] = __builtin_amdgcn_mfma_f32_16x16x32_bf16(    \
                    aF[kk][i], BF[kk][j], acc[QM][QN][i][j], 0, 0, 0);          \
    __builtin_amdgcn_s_setprio(0);                                              \
} while (0)

#define BAR_FENCE do {                                                          \
    __builtin_amdgcn_s_barrier();                                               \
    asm volatile("" ::: "memory");                                              \
} while (0)

__global__ __launch_bounds__(512, 2)
void gemm_dual(const __hip_bfloat16* __restrict__ A0, const __hip_bfloat16* __restrict__ W0,
               const float* __restrict__ bias0, __hip_bfloat16* __restrict__ out0, int K0,
               const __hip_bfloat16* __restrict__ A1, const __hip_bfloat16* __restrict__ W1,
               const float* __restrict__ bias1, __hip_bfloat16* __restrict__ out1, int K1) {
    __shared__ alignas(16) __hip_bfloat16 smem[65536];   // 128 KiB

    const __hip_bfloat16* A;  const __hip_bfloat16* W;
    const float* bias;        __hip_bfloat16* out;  int K;
    if (blockIdx.y == 0) { A = A0; W = W0; bias = bias0; out = out0; K = K0; }
    else                 { A = A1; W = W1; bias = bias1; out = out1; K = K1; }

    const int t    = threadIdx.x;
    const int lane = t & 63;
    const int wave = t >> 6;
    const int quad = lane >> 4;
    const int rl   = lane & 15;
    const int rl7  = lane & 7;
    const int wr   = wave >> 2;           // 2 waves along quadrant-M (64 rows)
    const int wc   = wave & 3;            // 4 waves along quadrant-N (32 cols)

    // XCD swizzle: 512 blocks/plane, 512 % 8 == 0 -> bijective simple form
    const int id  = blockIdx.x;
    const int swz = (id & 7) * 64 + (id >> 3);
    const int m0  = (swz >> 4) * 256;     // 32 M-tiles
    const int n0  = (swz & 15) * 256;     // 16 N-tiles

    const int r0 = t >> 3;                // staging: row within 64-row slice
    const int c0 = t & 7;                 // staging: 16B chunk col

    floatx4 acc[2][2][4][2];
    #pragma unroll
    for (int a = 0; a < 2; ++a)
        #pragma unroll
        for (int b = 0; b < 2; ++b)
            #pragma unroll
            for (int i = 0; i < 4; ++i)
                #pragma unroll
                for (int j = 0; j < 2; ++j)
                    acc[a][b][i][j] = (floatx4){0.f, 0.f, 0.f, 0.f};

    short8 aF[2][4], bF0[2][2], bF1[2][2];

    // prologue: stage tile 0 -> buf0 in canonical order [A0,B0,B1,A1]
    STAGE_HALF(A, m0, 0, 0, 0);
    STAGE_HALF(W, n0, 0, 0, 16384);
    STAGE_HALF(W, n0, 1, 0, 16384);
    STAGE_HALF(A, m0, 1, 0, 0);

    const int NT = K >> 6;
    for (int T = 0; T < NT - 1; ++T) {
        const int cur = T & 1;
        const __hip_bfloat16* Sb = smem + cur * 32768;
        const int nb = (cur ^ 1) * 32768;
        const int kn = (T + 1) << 6;
        // ph0: quadrant (0,0)
        STAGE_HALF(A, m0, 0, kn, nb);
        asm volatile("s_waitcnt vmcnt(6)" ::: "memory");
        BAR_FENCE;
        RDA(0); RDB(bF0, 0);
        MFMAQ(0, 0, bF0);
        // ph1: quadrant (0,1)
        STAGE_HALF(W, n0, 0, kn, nb + 16384);
        asm volatile("s_waitcnt vmcnt(6)" ::: "memory");
        BAR_FENCE;
        RDB(bF1, 1);
        MFMAQ(0, 1, bF1);
        // ph2: quadrant (1,1)
        STAGE_HALF(W, n0, 1, kn, nb + 16384);
        asm volatile("s_waitcnt vmcnt(6)" ::: "memory");
        BAR_FENCE;
        RDA(1);
        MFMAQ(1, 1, bF1);
        // ph3: quadrant (1,0) — registers only (aF from ph2, bF0 from ph0)
        STAGE_HALF(A, m0, 1, kn, nb);
        MFMAQ(1, 0, bF0);
        asm volatile("" ::: "memory");
        __builtin_amdgcn_s_barrier();   // tile-end: all T reads drained before
                                        // T+1 ph0 stages into buf[T&1]
        asm volatile("" ::: "memory");
    }
    {   // last tile: nothing staged during it -> drain 4 / 2 / 0 / none
        const int cur = (NT - 1) & 1;
        const __hip_bfloat16* Sb = smem + cur * 32768;
        asm volatile("s_waitcnt vmcnt(4)" ::: "memory");
        BAR_FENCE;
        RDA(0); RDB(bF0, 0);
        MFMAQ(0, 0, bF0);
        asm volatile("s_waitcnt vmcnt(2)" ::: "memory");
        BAR_FENCE;
        RDB(bF1, 1);
        MFMAQ(0, 1, bF1);
        asm volatile("s_waitcnt vmcnt(0)" ::: "memory");
        BAR_FENCE;
        RDA(1);
        MFMAQ(1, 1, bF1);
        MFMAQ(1, 0, bF0);
    }

    // epilogue: per qm-half LDS repack (stride 264) -> coalesced 16B stores
    __syncthreads();
    #pragma unroll
    for (int h = 0; h < 2; ++h) {
        #pragma unroll
        for (int qn = 0; qn < 2; ++qn)
            #pragma unroll
            for (int j = 0; j < 2; ++j) {
                const int col = qn * 128 + wc * 32 + j * 16 + rl;
                const float bv = bias[n0 + col];
                #pragma unroll
                for (int i = 0; i < 4; ++i) {
                    const int rbase = wr * 64 + i * 16 + quad * 4;
                    #pragma unroll
                    for (int rr = 0; rr < 4; ++rr)
                        smem[(rbase + rr) * 264 + col] = __float2bfloat16(acc[h][qn][i][j][rr] + bv);
                }
            }
        __syncthreads();
        #pragma unroll
        for (int p = 0; p < 8; ++p) {
            const int ch  = p * 512 + t;
            const int row = ch >> 5;
            const int c8  = (ch & 31) << 3;
            short8 v = *(const short8*)(smem + row * 264 + c8);
            *(short8*)(out + (size_t)(m0 + h * 128 + row) * 4096 + n0 + c8) = v;
        }
        __syncthreads();
    }
}

// ---------------------------------------------------------------------------
// Single-pass LN+gates, 4 rows per block, 512 threads (R4-verbatim).
// ---------------------------------------------------------------------------
__global__ __launch_bounds__(512)
void ln_gates(const __hip_bfloat16* __restrict__ Pi, const __hip_bfloat16* __restrict__ Ph,
              const float* __restrict__ c_prev,
              const float* __restrict__ g_in, const float* __restrict__ b_in,
              const float* __restrict__ g_hid, const float* __restrict__ b_hid,
              const float* __restrict__ g_cell, const float* __restrict__ b_cell,
              float* __restrict__ h_out, float* __restrict__ c_out) {
    const int t    = threadIdx.x;
    const int rid  = t >> 7;
    const int tt   = t & 127;
    const int wave = t >> 6;
    const int row  = blockIdx.x * 4 + rid;
    __shared__ float sred[8][6];

    const __hip_bfloat16* pi = Pi + (size_t)row * 4096;
    const __hip_bfloat16* ph = Ph + (size_t)row * 4096;
    const int j0 = tt * 8;

    float fpi[4][8], fph[4][8];
    float si = 0.f, sqi = 0.f, sh = 0.f, sqh = 0.f;
    #pragma unroll
    for (int g = 0; g < 4; ++g) {
        short8 vi = *(const short8*)(pi + g * 1024 + j0);
        short8 vh = *(const short8*)(ph + g * 1024 + j0);
        #pragma unroll
        for (int e = 0; e < 8; ++e) {
            const float a = b2f(vi[e]); fpi[g][e] = a; si += a; sqi += a * a;
            const float b = b2f(vh[e]); fph[g][e] = b; sh += b; sqh += b * b;
        }
    }
    floatx4 cp0 = *(const floatx4*)(c_prev + (size_t)row * 1024 + j0);
    floatx4 cp1 = *(const floatx4*)(c_prev + (size_t)row * 1024 + j0 + 4);

    #pragma unroll
    for (int mask = 1; mask <= 32; mask <<= 1) {
        si += __shfl_xor(si, mask); sqi += __shfl_xor(sqi, mask);
        sh += __shfl_xor(sh, mask); sqh += __shfl_xor(sqh, mask);
    }
    if ((t & 63) == 0) {
        sred[wave][0] = si; sred[wave][1] = sqi;
        sred[wave][2] = sh; sred[wave][3] = sqh;
    }
    __syncthreads();
    const int wb = rid * 2;
    si  = sred[wb][0] + sred[wb + 1][0];
    sqi = sred[wb][1] + sred[wb + 1][1];
    sh  = sred[wb][2] + sred[wb + 1][2];
    sqh = sred[wb][3] + sred[wb + 1][3];

    const float mu_i = si * (1.f / 4096.f);
    const float rs_i = rsqrtf(sqi * (1.f / 4096.f) - mu_i * mu_i + EPS);
    const float mu_h = sh * (1.f / 4096.f);
    const float rs_h = rsqrtf(sqh * (1.f / 4096.f) - mu_h * mu_h + EPS);

    float comb[4][8];
    #pragma unroll
    for (int g = 0; g < 4; ++g) {
        const int col = g * 1024 + j0;
        floatx4 gi0  = *(const floatx4*)(g_in  + col);
        floatx4 gi1  = *(const floatx4*)(g_in  + col + 4);
        floatx4 bi0  = *(const floatx4*)(b_in  + col);
        floatx4 bi1  = *(const floatx4*)(b_in  + col + 4);
        floatx4 gh0  = *(const floatx4*)(g_hid + col);
        floatx4 gh1  = *(const floatx4*)(g_hid + col + 4);
        floatx4 bh0  = *(const floatx4*)(b_hid + col);
        floatx4 bh1  = *(const floatx4*)(b_hid + col + 4);
        #pragma unroll
        for (int e = 0; e < 4; ++e) {
            comb[g][e]     = (fpi[g][e]     - mu_i) * rs_i * gi0[e] + bi0[e]
                           + (fph[g][e]     - mu_h) * rs_h * gh0[e] + bh0[e];
            comb[g][e + 4] = (fpi[g][e + 4] - mu_i) * rs_i * gi1[e] + bi1[e]
                           + (fph[g][e + 4] - mu_h) * rs_h * gh1[e] + bh1[e];
        }
    }

    float cn[8], ov[8];
    float sc = 0.f, scq = 0.f;
    #pragma unroll
    for (int e = 0; e < 8; ++e) {
        const float iv = sigmoidf_(comb[0][e]);
        const float fv = sigmoidf_(comb[1][e]);
        const float gv = tanhf_(comb[2][e]);
        ov[e] = sigmoidf_(comb[3][e]);
        const float cpv = (e < 4) ? cp0[e] : cp1[e - 4];
        const float c = fv * cpv + iv * gv;
        cn[e] = c; sc += c; scq += c * c;
    }
    #pragma unroll
    for (int mask = 1; mask <= 32; mask <<= 1) {
        sc += __shfl_xor(sc, mask); scq += __shfl_xor(scq, mask);
    }
    if ((t & 63) == 0) { sred[wave][4] = sc; sred[wave][5] = scq; }
    __syncthreads();
    sc  = sred[wb][4] + sred[wb + 1][4];
    scq = sred[wb][5] + sred[wb + 1][5];
    const float mu_c = sc * (1.f / 1024.f);
    const float rs_c = rsqrtf(scq * (1.f / 1024.f) - mu_c * mu_c + EPS);

    floatx4 gc0 = *(const floatx4*)(g_cell + j0);
    floatx4 gc1 = *(const floatx4*)(g_cell + j0 + 4);
    floatx4 bc0 = *(const floatx4*)(b_cell + j0);
    floatx4 bc1 = *(const floatx4*)(b_cell + j0 + 4);
    floatx4 hv0, hv1, cv0, cv1;
    #pragma unroll
    for (int e = 0; e < 4; ++e) {
        const float nc0 = (cn[e]     - mu_c) * rs_c * gc0[e] + bc0[e];
        const float nc1 = (cn[e + 4] - mu_c) * rs_c * gc1[e] + bc1[e];
        hv0[e] = ov[e] * tanhf_(nc0);
        hv1[e] = ov[e + 4] * tanhf_(nc1);
        cv0[e] = cn[e];
        cv1[e] = cn[e + 4];
    }
    float* hp = h_out + (size_t)row * 1024 + j0;
    float* cpout = c_out + (size_t)row * 1024 + j0;
    *(floatx4*)(hp) = hv0;     *(floatx4*)(hp + 4) = hv1;
    *(floatx4*)(cpout) = cv0;  *(floatx4*)(cpout + 4) = cv1;
}

// ---------------------------------------------------------------------------
extern "C" void kernel_launch(void* const* d_in, const int* in_sizes, int n_in,
                              void* d_out, int out_size, void* d_ws, size_t ws_size,
                              hipStream_t stream) {
    const float* x      = (const float*)d_in[0];
    const float* h_prev = (const float*)d_in[1];
    const float* c_prev = (const float*)d_in[2];
    const float* Wi     = (const float*)d_in[3];
    const float* bi     = (const float*)d_in[4];
    const float* Wh     = (const float*)d_in[5];
    const float* bh     = (const float*)d_in[6];
    const float* g_in   = (const float*)d_in[7];
    const float* b_in   = (const float*)d_in[8];
    const float* g_hid  = (const float*)d_in[9];
    const float* b_hid  = (const float*)d_in[10];
    const float* g_cell = (const float*)d_in[11];
    const float* b_cell = (const float*)d_in[12];

    __hip_bfloat16* Pi = (__hip_bfloat16*)d_ws;               // 64 MiB
    __hip_bfloat16* Ph = Pi + (size_t)8192 * 4096;            // 64 MiB

    const int NX = 8192 * 512, NH = 8192 * 1024;
    __hip_bfloat16* xb  = (__hip_bfloat16*)d_out;             // scratch in d_out
    __hip_bfloat16* hb  = xb + NX;
    __hip_bfloat16* Wib = hb + NH;
    __hip_bfloat16* Whb = Wib + 4096 * 512;

    float* h_out = (float*)d_out;
    float* c_out = h_out + (size_t)8192 * 1024;

    hipLaunchKernelGGL(cvt_bf16, dim3(9216), dim3(256), 0, stream,
                       x, xb, h_prev, hb, Wi, Wib, Wh, Whb);

    // 256^2 tiles: 32 M-tiles x 16 N-tiles = 512 blocks per GEMM, y = GEMM id
    hipLaunchKernelGGL(gemm_dual, dim3(512, 2), dim3(512), 0, stream,
                       xb, Wib, bi, Pi, 512,
                       hb, Whb, bh, Ph, 1024);

    hipLaunchKernelGGL(ln_gates, dim3(2048), dim3(512), 0, stream, Pi, Ph, c_prev,
                       g_in, b_in, g_hid, b_hid, g_cell, b_cell, h_out, c_out);
}